// Round 3
// baseline (187.343 us; speedup 1.0000x reference)
//
#include <hip/hip_runtime.h>

// Problem constants (hardcoded; spatial_shapes = [[4,8]]*4)
//  bs=64, nq=64, E=256, Hn=8, dh=32, L=4, P=16, BEV=2, Pb=32
//  qb=128 collapses to 64 (queries duplicated). OFF col (h,f,c)=h*256+2f+c;
//  rp level = f&3; image level = f>>5; attn key = f; output pairs (2q,2q+1).
//
// ws: [0,2M) Ab bf16 4096x256 | [2M,4M) Khb bf16 4096x256
//     [4M,8M) VTg bf16 [b*8+h][32 d][128 p] | [8M,24.8M) OFFb bf16 4096x2048

typedef short  s16x8 __attribute__((ext_vector_type(8)));
typedef short  s16x4 __attribute__((ext_vector_type(4)));
typedef float  f32x4 __attribute__((ext_vector_type(4)));

__device__ __forceinline__ unsigned short f2bf(float f) {
    union { float f; unsigned u; } v; v.f = f;
    unsigned r = v.u + 0x7FFFu + ((v.u >> 16) & 1u);   // RNE
    return (unsigned short)(r >> 16);
}

// ---------------------------------------------------------------------------
// prep: [0,1024) query->Ab ; [1024,2048) key_hist->Khb ;
//       [2048,2560) VT build per (b,h): VTg[bh][d][p] = values[p][d] bf16
// ---------------------------------------------------------------------------
__global__ __launch_bounds__(256) void prep(
    const float* __restrict__ query, const float* __restrict__ key_hist,
    const float* __restrict__ value_hist,
    short* __restrict__ Ab, short* __restrict__ Khb, short* __restrict__ VTg)
{
    const int job = blockIdx.x, t = threadIdx.x;
    if (job < 2048) {
        const bool isK = job >= 1024;
        const float* src = isK ? key_hist : query;
        short* dst = isK ? Khb : Ab;
        const int i4 = ((job & 1023) * 256 + t) * 4;
        const float4 v = *(const float4*)(src + i4);
        s16x4 o;
        o.x = (short)f2bf(v.x); o.y = (short)f2bf(v.y);
        o.z = (short)f2bf(v.z); o.w = (short)f2bf(v.w);
        *(s16x4*)(dst + i4) = o;
    } else {
        const int bh = job - 2048;           // 0..511
        const int b = bh >> 3, h = bh & 7;
        #pragma unroll
        for (int pass = 0; pass < 4; ++pass) {
            const int idx = t + 256 * pass;  // 0..1023
            const int p = idx >> 3;          // 0..127
            const int dg = idx & 7;          // 0..7
            const float* src = (p < 64) ? query : value_hist;
            const float4 v = *(const float4*)(src +
                (size_t)(b * 64 + (p & 63)) * 256 + h * 32 + dg * 4);
            short* o = VTg + ((size_t)bh * 32 + dg * 4) * 128 + p;
            o[0 * 128] = (short)f2bf(v.x);
            o[1 * 128] = (short)f2bf(v.y);
            o[2 * 128] = (short)f2bf(v.z);
            o[3 * 128] = (short)f2bf(v.w);
        }
    }
}

// ---------------------------------------------------------------------------
// OFFb[4096][2048] = bf16( Ab @ W^T(staged) + bias )
// 128x128 tile, 4 waves 2x2, 4x4 MFMA 16x16x32 each. W transposed+converted
// during staging. Epilogue repacks via LDS for coalesced dwordx4 stores.
// ---------------------------------------------------------------------------
__global__ __launch_bounds__(256) void offs_gemm_mfma(
    const short* __restrict__ Ab, const float* __restrict__ W,
    const float* __restrict__ bias, short* __restrict__ OFFb)
{
    __shared__ __align__(16) short smem[128 * 136];   // 34.8 KB
    short (*Asl)[40] = (short (*)[40])smem;           // [m][k]
    short (*Bsl)[40] = (short (*)[40])(smem + 128 * 40);
    short (*Cst)[136] = (short (*)[136])smem;         // epilogue alias

    const int n0 = blockIdx.x * 128, m0 = blockIdx.y * 128;
    const int t = threadIdx.x, lane = t & 63, wave = t >> 6;
    const int wm0 = (wave >> 1) * 64, wn0 = (wave & 1) * 64;
    const int r = lane & 15, q = lane >> 4;

    f32x4 acc[4][4] = {};

    for (int kc = 0; kc < 256; kc += 32) {
        #pragma unroll
        for (int ss = 0; ss < 2; ++ss) {            // A: bf16 dwordx4
            const int seg = t + ss * 256;
            const int row = seg >> 2, off8 = (seg & 3) * 8;
            *(s16x8*)&Asl[row][off8] =
                *(const s16x8*)(Ab + (size_t)(m0 + row) * 256 + kc + off8);
        }
        #pragma unroll
        for (int i = 0; i < 4; ++i) {               // B: W fp32 -> bf16 transposed
            const int slot = t + 256 * i;
            const int kk = slot >> 5, n4 = (slot & 31) * 4;
            const float4 w4 = *(const float4*)(W + (size_t)(kc + kk) * 2048 + n0 + n4);
            Bsl[n4 + 0][kk] = (short)f2bf(w4.x);
            Bsl[n4 + 1][kk] = (short)f2bf(w4.y);
            Bsl[n4 + 2][kk] = (short)f2bf(w4.z);
            Bsl[n4 + 3][kk] = (short)f2bf(w4.w);
        }
        __syncthreads();
        s16x8 af[4], bf[4];
        #pragma unroll
        for (int i = 0; i < 4; ++i) {
            af[i] = *(const s16x8*)&Asl[wm0 + i * 16 + r][q * 8];
            bf[i] = *(const s16x8*)&Bsl[wn0 + i * 16 + r][q * 8];
        }
        #pragma unroll
        for (int i = 0; i < 4; ++i)
            #pragma unroll
            for (int j = 0; j < 4; ++j)
                acc[i][j] = __builtin_amdgcn_mfma_f32_16x16x32_bf16(
                    af[i], bf[j], acc[i][j], 0, 0, 0);
        __syncthreads();
    }

    // epilogue: bias + bf16 into Cst (C/D: col=lane&15, row=quad*4+reg)
    #pragma unroll
    for (int j = 0; j < 4; ++j) {
        const float bb = bias[n0 + wn0 + j * 16 + r];
        #pragma unroll
        for (int i = 0; i < 4; ++i)
            #pragma unroll
            for (int rg = 0; rg < 4; ++rg)
                Cst[wm0 + i * 16 + q * 4 + rg][wn0 + j * 16 + r] =
                    (short)f2bf(acc[i][j][rg] + bb);
    }
    __syncthreads();
    {
        const int row = t >> 1, half = t & 1;
        short* gdst = OFFb + (size_t)(m0 + row) * 2048 + n0 + half * 64;
        const short* lsrc = &Cst[row][half * 64];
        #pragma unroll
        for (int u = 0; u < 8; ++u)
            *(s16x8*)(gdst + u * 8) = *(const s16x8*)(lsrc + u * 8);
    }
}

// ---------------------------------------------------------------------------
// fused_tsa2: one block per (h,b), 256 threads (4 waves), all 64 queries.
// MFMA logits (global bf16 frags) -> in-register softmax -> LDS scatter ->
// bf16 convert -> MFMA AV (VT global) -> pair-mean + residual.
// ---------------------------------------------------------------------------
__global__ __launch_bounds__(256) void fused_tsa2(
    const float* __restrict__ query, const float* __restrict__ refp,
    const short* __restrict__ Ab, const short* __restrict__ Khb,
    const short* __restrict__ VTg, const unsigned* __restrict__ OFFu,
    float* __restrict__ out)
{
    const int h = blockIdx.x, b = blockIdx.y;
    const int t = threadIdx.x, lane = t & 63, wave = t >> 6;
    const int quad = lane >> 4, col = lane & 15;
    const int wq = wave * 16;

    __shared__ __align__(16) float Am[64][132];       // 33.8 KB fp32
    short* Amb = (short*)&Am[0][0];                   // alias: [64][136] bf16

    // ---- prefetch OFF dwords + ref points (independent of everything) ----
    unsigned off_u[8][4];
    {
        const unsigned* ob = OFFu + ((size_t)b * 64 + wq + quad * 4) * 1024 + h * 128 + col;
        #pragma unroll
        for (int r = 0; r < 4; ++r)
            #pragma unroll
            for (int t8 = 0; t8 < 8; ++t8)
                off_u[t8][r] = ob[r * 1024 + t8 * 16];
    }
    float rpx[4], rpy[4];
    #pragma unroll
    for (int r = 0; r < 4; ++r) {
        const float2 rp = *(const float2*)(refp +
            ((size_t)b * 64 + wq + quad * 4 + r) * 8 + (lane & 3) * 2);
        rpx[r] = rp.x; rpy[r] = rp.y;
    }

    // ---- zero Am ----
    {
        const int zq = t >> 2, zc = (t & 3) * 32;
        const float4 z = {0.f, 0.f, 0.f, 0.f};
        #pragma unroll
        for (int u = 0; u < 8; ++u) *(float4*)&Am[zq][zc + 4 * u] = z;
    }

    // ---- logits: M=64 q (m-tile=wave), N=128 k, K=32 d ----
    const s16x8 aq = *(const s16x8*)(Ab +
        ((size_t)b * 64 + wq + col) * 256 + h * 32 + quad * 8);
    f32x4 acc[8];
    #pragma unroll
    for (int t8 = 0; t8 < 8; ++t8) {
        const int n = t8 * 16 + col;
        const short* src = (t8 < 4)
            ? (Ab  + ((size_t)b * 64 + n) * 256)
            : (Khb + ((size_t)b * 64 + n - 64) * 256);
        const s16x8 bk = *(const s16x8*)(src + h * 32 + quad * 8);
        const f32x4 z = {0.f, 0.f, 0.f, 0.f};
        acc[t8] = __builtin_amdgcn_mfma_f32_16x16x32_bf16(aq, bk, z, 0, 0, 0);
    }

    // ---- softmax per q-row, entirely in registers (16-lane groups) ----
    float att[8][4];
    #pragma unroll
    for (int r = 0; r < 4; ++r) {
        float m = acc[0][r];
        #pragma unroll
        for (int t8 = 1; t8 < 8; ++t8) m = fmaxf(m, acc[t8][r]);
        #pragma unroll
        for (int s = 1; s < 16; s <<= 1) m = fmaxf(m, __shfl_xor(m, s, 64));
        float ssum = 0.f;
        #pragma unroll
        for (int t8 = 0; t8 < 8; ++t8) {
            const float e = __expf(acc[t8][r] - m);
            att[t8][r] = e; ssum += e;
        }
        #pragma unroll
        for (int s = 1; s < 16; s <<= 1) ssum += __shfl_xor(ssum, s, 64);
        const float inv = 1.0f / ssum;
        #pragma unroll
        for (int t8 = 0; t8 < 8; ++t8) att[t8][r] *= inv;
    }
    __syncthreads();   // Am zeroed by all waves

    // ---- scatter attn * bilinear weights into Am[q][pos] ----
    #pragma unroll
    for (int t8 = 0; t8 < 8; ++t8) {
        const int f = col + 16 * t8;
        const int base = (f >> 5) * 32;
        #pragma unroll
        for (int r = 0; r < 4; ++r) {
            float* rowW = &Am[wq + quad * 4 + r][0];
            const float a = att[t8][r];
            const unsigned u = off_u[t8][r];
            const float ox = __uint_as_float(u << 16);
            const float oy = __uint_as_float(u & 0xFFFF0000u);
            const float gx = 8.f * (rpx[r] + ox * 0.125f) - 0.5f;
            const float gy = 4.f * (rpy[r] + oy * 0.25f) - 0.5f;
            const float x0f = floorf(gx), y0f = floorf(gy);
            const float wx = gx - x0f, wy = gy - y0f;
            const int x0 = (int)x0f, y0 = (int)y0f;
            const bool xv0 = (x0 >= 0) && (x0 < 8);
            const bool xv1 = (x0 >= -1) && (x0 < 7);
            const bool yv0 = (y0 >= 0) && (y0 < 4);
            const bool yv1 = (y0 >= -1) && (y0 < 3);
            if (xv0 && yv0) atomicAdd(&rowW[base + y0 * 8 + x0],           a * (1.f - wx) * (1.f - wy));
            if (xv1 && yv0) atomicAdd(&rowW[base + y0 * 8 + x0 + 1],       a * wx * (1.f - wy));
            if (xv0 && yv1) atomicAdd(&rowW[base + (y0 + 1) * 8 + x0],     a * (1.f - wx) * wy);
            if (xv1 && yv1) atomicAdd(&rowW[base + (y0 + 1) * 8 + x0 + 1], a * wx * wy);
        }
    }
    __syncthreads();

    // ---- convert Am fp32 -> bf16 (in place via registers) ----
    {
        const int cq = t >> 2, cc = (t & 3) * 32;
        float vreg[32];
        #pragma unroll
        for (int u = 0; u < 8; ++u) {
            const float4 v = *(const float4*)&Am[cq][cc + 4 * u];
            vreg[4 * u + 0] = v.x; vreg[4 * u + 1] = v.y;
            vreg[4 * u + 2] = v.z; vreg[4 * u + 3] = v.w;
        }
        __syncthreads();
        #pragma unroll
        for (int u = 0; u < 4; ++u) {
            s16x8 o;
            #pragma unroll
            for (int j = 0; j < 8; ++j) o[j] = (short)f2bf(vreg[u * 8 + j]);
            *(s16x8*)&Amb[cq * 136 + cc + u * 8] = o;
        }
    }
    __syncthreads();

    // ---- AV: M=64 q, N=32 d (2 tiles), K=128 p (4 steps) ----
    f32x4 oacc[2] = {};
    #pragma unroll
    for (int ks = 0; ks < 4; ++ks) {
        const s16x8 af = *(const s16x8*)&Amb[(wq + col) * 136 + ks * 32 + quad * 8];
        #pragma unroll
        for (int n2 = 0; n2 < 2; ++n2) {
            const s16x8 bv = *(const s16x8*)(VTg +
                ((size_t)(b * 8 + h) * 32 + n2 * 16 + col) * 128 + ks * 32 + quad * 8);
            oacc[n2] = __builtin_amdgcn_mfma_f32_16x16x32_bf16(af, bv, oacc[n2], 0, 0, 0);
        }
    }

    // ---- pair-mean (regs 2r,2r+1 in-lane) + residual; rows pj / pj+32 ----
    #pragma unroll
    for (int n2 = 0; n2 < 2; ++n2) {
        const int d = h * 32 + n2 * 16 + col;
        #pragma unroll
        for (int pr = 0; pr < 2; ++pr) {
            const float avg = 0.5f * (oacc[n2][2 * pr] + oacc[n2][2 * pr + 1]);
            const int pj = wave * 8 + quad * 2 + pr;
            const size_t re = ((size_t)b * 64 + pj) * 256 + d;
            const size_t ro = ((size_t)b * 64 + pj + 32) * 256 + d;
            out[re] = query[re] + avg;
            out[ro] = query[ro] + avg;
        }
    }
}

extern "C" void kernel_launch(void* const* d_in, const int* in_sizes, int n_in,
                              void* d_out, int out_size, void* d_ws, size_t ws_size,
                              hipStream_t stream) {
    (void)in_sizes; (void)n_in; (void)out_size; (void)ws_size;
    const float* query      = (const float*)d_in[0];
    const float* key_hist   = (const float*)d_in[1];
    const float* value_hist = (const float*)d_in[2];
    const float* refp       = (const float*)d_in[3];
    const float* W_off      = (const float*)d_in[5];
    const float* b_off      = (const float*)d_in[6];

    char* ws = (char*)d_ws;
    short* Ab   = (short*)(ws);                       // 2 MB
    short* Khb  = (short*)(ws + (2u << 20));          // 2 MB
    short* VTg  = (short*)(ws + (4u << 20));          // 4 MB
    short* OFFb = (short*)(ws + (8u << 20));          // 16.78 MB
    float* out  = (float*)d_out;

    prep<<<2560, 256, 0, stream>>>(query, key_hist, value_hist, Ab, Khb, VTg);
    offs_gemm_mfma<<<dim3(16, 32), 256, 0, stream>>>(Ab, W_off, b_off, OFFb);
    fused_tsa2<<<dim3(8, 64), 256, 0, stream>>>(query, refp, Ab, Khb, VTg,
                                                (const unsigned*)OFFb, out);
}

// Round 4
// 165.399 us; speedup vs baseline: 1.1327x; 1.1327x over previous
//
#include <hip/hip_runtime.h>

// Problem constants (hardcoded; spatial_shapes = [[4,8]]*4)
//  bs=64, nq=64, E=256, Hn=8, dh=32, L=4, P=16, BEV=2, Pb=32
//  qb=128 collapses to 64 (queries duplicated). OFF col (h,f,c)=h*256+2f+c;
//  rp level = f&3 = i&3; image level = f>>5 = wave; attn key = f;
//  output pairs (2q,2q+1) -> rows pj / pj+32.
//
// ws: [0,1MB) Wtb bf16 [2048 n][256 k]  (W_off transposed)

typedef short  s16x8 __attribute__((ext_vector_type(8)));
typedef short  s16x4 __attribute__((ext_vector_type(4)));
typedef float  f32x4 __attribute__((ext_vector_type(4)));

__device__ __forceinline__ unsigned short f2bf(float f) {
    union { float f; unsigned u; } v; v.f = f;
    unsigned r = v.u + 0x7FFFu + ((v.u >> 16) & 1u);   // RNE
    return (unsigned short)(r >> 16);
}

// ---------------------------------------------------------------------------
// W_off [256][2048] f32 -> Wtb [2048][256] bf16 (32x32 LDS tile transpose)
// ---------------------------------------------------------------------------
__global__ __launch_bounds__(256) void transp_bf16(const float* __restrict__ W,
                                                   short* __restrict__ Wt) {
    __shared__ float s[32][33];
    const int n0 = blockIdx.x * 32, k0 = blockIdx.y * 32;
    const int c = threadIdx.x & 31, r0 = threadIdx.x >> 5;
    #pragma unroll
    for (int p = 0; p < 4; ++p) {
        const int r = r0 + p * 8;
        s[r][c] = W[(size_t)(k0 + r) * 2048 + n0 + c];
    }
    __syncthreads();
    #pragma unroll
    for (int p = 0; p < 4; ++p) {
        const int r = r0 + p * 8;
        Wt[(size_t)(n0 + r) * 256 + k0 + c] = (short)f2bf(s[c][r]);
    }
}

// ---------------------------------------------------------------------------
// mega_tsa: one block per (h,b). Everything fused:
//  logits MFMA -> reg softmax -> attL | offsets GEMM (M64 N256 K256 MFMA,
//  OFF stays in registers) -> shfl xy-pairing -> bilinear scatter into Am
//  -> bf16 -> AV MFMA -> pair-mean + residual.
// LDS 117.5 KB -> 1 block/CU.
// ---------------------------------------------------------------------------
__global__ __launch_bounds__(256, 1) void mega_tsa(
    const float* __restrict__ query, const float* __restrict__ key_hist,
    const float* __restrict__ value_hist, const float* __restrict__ refp,
    const short* __restrict__ Wtb, const float* __restrict__ bias,
    float* __restrict__ out)
{
    const int h = blockIdx.x, b = blockIdx.y;
    const int t = threadIdx.x, lane = t & 63, wave = t >> 6;
    const int quad = lane >> 4, col = lane & 15;
    const int wq = wave * 16;

    __shared__ __align__(16) short Asl[64 * 264];   // [m][k] query bf16, 33792 B
    __shared__ __align__(16) short Khl[64 * 40];    // key_hist h-slice, 5120 B
    __shared__ __align__(16) short VTl[32 * 136];   // V^T [d][p], 8704 B
    __shared__ __align__(16) float attL[64 * 132];  // att probs f32, 33792 B
    __shared__ __align__(16) float rpsL[512];       // refp rows, 2048 B
    __shared__ __align__(16) float AmU[9216];       // 36864 B: Bsl / Am / Amb
    short* Bsl = (short*)AmU;                       // [4][64][72] bf16
    float* Am  = AmU;                               // [64][132] f32
    short* Amb = (short*)AmU;                       // [64][136] bf16

    // ================= Phase 0: stage =================
    {   // Asl: query rows (b*64..+63), all 256 k, f32->bf16
        const int row = t >> 2, seg = (t & 3) * 64;
        const float* src = query + (size_t)(b * 64 + row) * 256 + seg;
        #pragma unroll
        for (int u = 0; u < 16; ++u) {
            const float4 v = *(const float4*)(src + 4 * u);
            s16x4 o;
            o.x = (short)f2bf(v.x); o.y = (short)f2bf(v.y);
            o.z = (short)f2bf(v.z); o.w = (short)f2bf(v.w);
            *(s16x4*)&Asl[row * 264 + seg + 4 * u] = o;
        }
    }
    {   // Khl: key_hist h-slice
        const int row = t >> 2, s8 = (t & 3) * 8;
        const float* src = key_hist + (size_t)(b * 64 + row) * 256 + h * 32 + s8;
        #pragma unroll
        for (int u = 0; u < 2; ++u) {
            const float4 v = *(const float4*)(src + 4 * u);
            s16x4 o;
            o.x = (short)f2bf(v.x); o.y = (short)f2bf(v.y);
            o.z = (short)f2bf(v.z); o.w = (short)f2bf(v.w);
            *(s16x4*)&Khl[row * 40 + s8 + 4 * u] = o;
        }
    }
    {   // VTl[d][p]: values = [query rows | value_hist rows] h-slice, transposed
        const int p = t >> 1, hf = (t & 1) * 16;
        const float* src = ((p < 64) ? query : value_hist) +
                           (size_t)(b * 64 + (p & 63)) * 256 + h * 32 + hf;
        #pragma unroll
        for (int u = 0; u < 4; ++u) {
            const float4 v = *(const float4*)(src + 4 * u);
            VTl[(hf + 4 * u + 0) * 136 + p] = (short)f2bf(v.x);
            VTl[(hf + 4 * u + 1) * 136 + p] = (short)f2bf(v.y);
            VTl[(hf + 4 * u + 2) * 136 + p] = (short)f2bf(v.z);
            VTl[(hf + 4 * u + 3) * 136 + p] = (short)f2bf(v.w);
        }
    }
    {   // rpsL: refp rows (64 q x 8)
        rpsL[t]       = refp[(size_t)b * 512 + t];
        rpsL[t + 256] = refp[(size_t)b * 512 + t + 256];
    }
    __syncthreads();

    // ================= Phase 1: logits + softmax -> attL =================
    {
        const s16x8 aq = *(const s16x8*)&Asl[(wq + col) * 264 + h * 32 + quad * 8];
        f32x4 lacc[8];
        #pragma unroll
        for (int t8 = 0; t8 < 8; ++t8) {
            const s16x8 bk = (t8 < 4)
                ? *(const s16x8*)&Asl[(16 * t8 + col) * 264 + h * 32 + quad * 8]
                : *(const s16x8*)&Khl[(16 * (t8 - 4) + col) * 40 + quad * 8];
            const f32x4 z = {0.f, 0.f, 0.f, 0.f};
            lacc[t8] = __builtin_amdgcn_mfma_f32_16x16x32_bf16(aq, bk, z, 0, 0, 0);
        }
        #pragma unroll
        for (int r = 0; r < 4; ++r) {
            float m = lacc[0][r];
            #pragma unroll
            for (int t8 = 1; t8 < 8; ++t8) m = fmaxf(m, lacc[t8][r]);
            #pragma unroll
            for (int s = 1; s < 16; s <<= 1) m = fmaxf(m, __shfl_xor(m, s, 64));
            float e[8], ssum = 0.f;
            #pragma unroll
            for (int t8 = 0; t8 < 8; ++t8) {
                e[t8] = __expf(lacc[t8][r] - m); ssum += e[t8];
            }
            #pragma unroll
            for (int s = 1; s < 16; s <<= 1) ssum += __shfl_xor(ssum, s, 64);
            const float inv = 1.0f / ssum;
            const int q = wq + 4 * quad + r;
            #pragma unroll
            for (int t8 = 0; t8 < 8; ++t8)
                attL[q * 132 + 16 * t8 + col] = e[t8] * inv;
        }
    }
    __syncthreads();

    // ================= Phase 2: offsets GEMM (OFF in registers) =============
    // wave owns n' in [64*wave, 64*wave+64): acc[mi][nj], q=16mi+4quad+r,
    // n' = 64*wave + 16nj + col.
    f32x4 acc[4][4] = {};
    for (int kq = 0; kq < 4; ++kq) {
        #pragma unroll
        for (int u = 0; u < 8; ++u) {       // stage Bsl[4][64][72] <- Wtb
            const int g = t + 256 * u;
            const int w = g >> 9, rowu = (g >> 3) & 63, koff = (g & 7) * 8;
            *(s16x8*)&Bsl[(w * 64 + rowu) * 72 + koff] =
                *(const s16x8*)(Wtb + (size_t)(h * 256 + w * 64 + rowu) * 256
                                + kq * 64 + koff);
        }
        __syncthreads();
        #pragma unroll
        for (int ks = 0; ks < 2; ++ks) {
            const int kk = kq * 64 + ks * 32 + quad * 8;
            s16x8 af[4], bf[4];
            #pragma unroll
            for (int mi = 0; mi < 4; ++mi)
                af[mi] = *(const s16x8*)&Asl[(16 * mi + col) * 264 + kk];
            #pragma unroll
            for (int nj = 0; nj < 4; ++nj)
                bf[nj] = *(const s16x8*)&Bsl[(wave * 64 + 16 * nj + col) * 72
                                             + ks * 32 + quad * 8];
            #pragma unroll
            for (int mi = 0; mi < 4; ++mi)
                #pragma unroll
                for (int nj = 0; nj < 4; ++nj)
                    acc[mi][nj] = __builtin_amdgcn_mfma_f32_16x16x32_bf16(
                        af[mi], bf[nj], acc[mi][nj], 0, 0, 0);
        }
        __syncthreads();
    }

    // ================= Phase 3: zero Am, scatter =================
    {
        #pragma unroll
        for (int u = 0; u < 33; ++u) AmU[t + 256 * u] = 0.f;
    }
    __syncthreads();
    {
        const int i   = col >> 1;          // f-sub 0..7 ; level l = i&3
        const int par = col & 1;           // 0: regs {0,1}, 1: regs {2,3}
        const int base = 32 * wave;        // level base = (f>>5)*32
        #pragma unroll
        for (int nj = 0; nj < 4; ++nj) {
            const float bj = bias[h * 256 + wave * 64 + 16 * nj + col];
            const int f = 32 * wave + 8 * nj + i;
            #pragma unroll
            for (int mi = 0; mi < 4; ++mi) {
                float v[4], p[4];
                #pragma unroll
                for (int r = 0; r < 4; ++r) v[r] = acc[mi][nj][r] + bj;
                #pragma unroll
                for (int r = 0; r < 4; ++r) p[r] = __shfl_xor(v[r], 1, 64);
                #pragma unroll
                for (int rs = 0; rs < 2; ++rs) {
                    const int r = par * 2 + rs;
                    const float ox = par ? p[r] : v[r];
                    const float oy = par ? v[r] : p[r];
                    const int q = 16 * mi + 4 * quad + r;
                    const float2 rp = *(const float2*)&rpsL[q * 8 + (i & 3) * 2];
                    const float a = attL[q * 132 + f];
                    const float gx = 8.f * (rp.x + ox * 0.125f) - 0.5f;
                    const float gy = 4.f * (rp.y + oy * 0.25f) - 0.5f;
                    const float x0f = floorf(gx), y0f = floorf(gy);
                    const float wx = gx - x0f, wy = gy - y0f;
                    const int x0 = (int)x0f, y0 = (int)y0f;
                    float* rowW = &Am[q * 132 + base];
                    const bool xv0 = (x0 >= 0) && (x0 < 8);
                    const bool xv1 = (x0 >= -1) && (x0 < 7);
                    const bool yv0 = (y0 >= 0) && (y0 < 4);
                    const bool yv1 = (y0 >= -1) && (y0 < 3);
                    if (xv0 && yv0) atomicAdd(&rowW[y0 * 8 + x0],           a * (1.f - wx) * (1.f - wy));
                    if (xv1 && yv0) atomicAdd(&rowW[y0 * 8 + x0 + 1],       a * wx * (1.f - wy));
                    if (xv0 && yv1) atomicAdd(&rowW[(y0 + 1) * 8 + x0],     a * (1.f - wx) * wy);
                    if (xv1 && yv1) atomicAdd(&rowW[(y0 + 1) * 8 + x0 + 1], a * wx * wy);
                }
            }
        }
    }
    __syncthreads();

    // ================= Phase 4: Am -> bf16, AV, output =================
    {
        const int cq = t >> 2, cc = (t & 3) * 32;
        float vreg[32];
        #pragma unroll
        for (int u = 0; u < 8; ++u) {
            const float4 v = *(const float4*)&Am[cq * 132 + cc + 4 * u];
            vreg[4 * u + 0] = v.x; vreg[4 * u + 1] = v.y;
            vreg[4 * u + 2] = v.z; vreg[4 * u + 3] = v.w;
        }
        __syncthreads();
        #pragma unroll
        for (int u = 0; u < 4; ++u) {
            s16x8 o;
            #pragma unroll
            for (int j = 0; j < 8; ++j) o[j] = (short)f2bf(vreg[u * 8 + j]);
            *(s16x8*)&Amb[cq * 136 + cc + u * 8] = o;
        }
    }
    __syncthreads();
    {
        f32x4 oacc[2] = {};
        #pragma unroll
        for (int ks = 0; ks < 4; ++ks) {
            const s16x8 af = *(const s16x8*)&Amb[(wq + col) * 136 + ks * 32 + quad * 8];
            #pragma unroll
            for (int n2 = 0; n2 < 2; ++n2) {
                const s16x8 bv = *(const s16x8*)&VTl[(n2 * 16 + col) * 136
                                                     + ks * 32 + quad * 8];
                oacc[n2] = __builtin_amdgcn_mfma_f32_16x16x32_bf16(af, bv, oacc[n2], 0, 0, 0);
            }
        }
        #pragma unroll
        for (int n2 = 0; n2 < 2; ++n2) {
            const int d = h * 32 + n2 * 16 + col;
            #pragma unroll
            for (int pr = 0; pr < 2; ++pr) {
                const float avg = 0.5f * (oacc[n2][2 * pr] + oacc[n2][2 * pr + 1]);
                const int pj = wave * 8 + quad * 2 + pr;
                const size_t re = ((size_t)b * 64 + pj) * 256 + d;
                const size_t ro = ((size_t)b * 64 + pj + 32) * 256 + d;
                out[re] = query[re] + avg;
                out[ro] = query[ro] + avg;
            }
        }
    }
}

extern "C" void kernel_launch(void* const* d_in, const int* in_sizes, int n_in,
                              void* d_out, int out_size, void* d_ws, size_t ws_size,
                              hipStream_t stream) {
    (void)in_sizes; (void)n_in; (void)out_size; (void)ws_size;
    const float* query      = (const float*)d_in[0];
    const float* key_hist   = (const float*)d_in[1];
    const float* value_hist = (const float*)d_in[2];
    const float* refp       = (const float*)d_in[3];
    const float* W_off      = (const float*)d_in[5];
    const float* b_off      = (const float*)d_in[6];

    short* Wtb = (short*)d_ws;            // 2048x256 bf16 = 1 MB
    float* out = (float*)d_out;

    transp_bf16<<<dim3(64, 8), 256, 0, stream>>>(W_off, Wtb);
    mega_tsa<<<dim3(8, 64), 256, 0, stream>>>(query, key_hist, value_hist,
                                              refp, Wtb, b_off, out);
}

// Round 5
// 162.190 us; speedup vs baseline: 1.1551x; 1.0198x over previous
//
#include <hip/hip_runtime.h>

// Problem constants (hardcoded; spatial_shapes = [[4,8]]*4)
//  bs=64, nq=64, E=256, Hn=8, dh=32, L=4, P=16, BEV=2, Pb=32
//  qb=128 collapses to 64 (queries duplicated). OFF col (h,f,c)=h*256+2f+c;
//  rp level = f&3; image level = f>>5 = wave; attn key = f;
//  output pairs (2q,2q+1) -> rows pj / pj+32.
//
// ws: [0,1M) Wtb bf16 [2048][256] | [1M,3M) Qb bf16 [4096][256]
//     [3M,5M) Khb bf16 [4096][256]

typedef short  s16x8 __attribute__((ext_vector_type(8)));
typedef short  s16x4 __attribute__((ext_vector_type(4)));
typedef float  f32x4 __attribute__((ext_vector_type(4)));

__device__ __forceinline__ unsigned short f2bf(float f) {
    union { float f; unsigned u; } v; v.f = f;
    unsigned r = v.u + 0x7FFFu + ((v.u >> 16) & 1u);   // RNE
    return (unsigned short)(r >> 16);
}
__device__ __forceinline__ float bf2f(unsigned short u) {
    return __uint_as_float(((unsigned)u) << 16);
}

// ---------------------------------------------------------------------------
// prep: [0,512) W transpose f32->bf16 ; [512,1536) query->Qb ;
//       [1536,2560) key_hist->Khb
// ---------------------------------------------------------------------------
__global__ __launch_bounds__(256) void prep(
    const float* __restrict__ W, const float* __restrict__ query,
    const float* __restrict__ key_hist,
    short* __restrict__ Wtb, short* __restrict__ Qb, short* __restrict__ Khb)
{
    __shared__ float s[32][33];
    const int bx = blockIdx.x, t = threadIdx.x;
    if (bx < 512) {
        const int n0 = (bx & 63) * 32, k0 = (bx >> 6) * 32;
        const int c = t & 31, r0 = t >> 5;
        #pragma unroll
        for (int p = 0; p < 4; ++p) {
            const int r = r0 + p * 8;
            s[r][c] = W[(size_t)(k0 + r) * 2048 + n0 + c];
        }
        __syncthreads();
        #pragma unroll
        for (int p = 0; p < 4; ++p) {
            const int r = r0 + p * 8;
            Wtb[(size_t)(n0 + r) * 256 + k0 + c] = (short)f2bf(s[c][r]);
        }
    } else {
        const int j = bx - 512;
        const bool isK = j >= 1024;
        const float* src = isK ? key_hist : query;
        short* dst = isK ? Khb : Qb;
        const int i4 = ((j & 1023) * 256 + t) * 4;
        const float4 v = *(const float4*)(src + i4);
        s16x4 o;
        o.x = (short)f2bf(v.x); o.y = (short)f2bf(v.y);
        o.z = (short)f2bf(v.z); o.w = (short)f2bf(v.w);
        *(s16x4*)(dst + i4) = o;
    }
}

// ---------------------------------------------------------------------------
// mega2: one block per (h,b). LDS 63.5 KB -> 2 blocks/CU.
// logits MFMA (operands direct from Qb/Khb) -> reg softmax -> attLb bf16 |
// offsets GEMM (A-frags direct from Qb, W staged in LDS; OFF in registers) ->
// shfl xy-pairing -> bilinear scatter (ds_add_f32 via unsafeAtomicAdd) ->
// bf16 -> AV MFMA -> pair-mean + residual.
// ---------------------------------------------------------------------------
__global__ __launch_bounds__(256, 2) void mega2(
    const float* __restrict__ query, const float* __restrict__ value_hist,
    const float* __restrict__ refp,
    const short* __restrict__ Qb, const short* __restrict__ Khb,
    const short* __restrict__ Wtb, const float* __restrict__ bias,
    float* __restrict__ out)
{
    const int h = blockIdx.x, b = blockIdx.y;
    const int t = threadIdx.x, lane = t & 63, wave = t >> 6;
    const int quad = lane >> 4, col = lane & 15;
    const int wq = wave * 16;

    __shared__ __align__(16) short VTl[32 * 136];   // V^T [d][p], 8704 B
    __shared__ __align__(16) short attLb[64 * 136]; // att probs bf16, 17408 B
    __shared__ __align__(16) float rpsL[512];       // refp rows, 2048 B
    __shared__ __align__(16) float AmU[9216];       // 36864 B: Bsl / Am / Amb
    short* Bsl = (short*)AmU;                       // [4][64][72] bf16
    float* Am  = AmU;                               // [64][132] f32
    short* Amb = (short*)AmU;                       // [64][136] bf16

    // ================= Phase 0: stage VTl + rps =================
    {   // VTl[d][p]: values = [query rows | value_hist rows] h-slice, transposed
        const int p = t >> 1, hf = (t & 1) * 16;
        const float* src = ((p < 64) ? query : value_hist) +
                           (size_t)(b * 64 + (p & 63)) * 256 + h * 32 + hf;
        #pragma unroll
        for (int u = 0; u < 4; ++u) {
            const float4 v = *(const float4*)(src + 4 * u);
            VTl[(hf + 4 * u + 0) * 136 + p] = (short)f2bf(v.x);
            VTl[(hf + 4 * u + 1) * 136 + p] = (short)f2bf(v.y);
            VTl[(hf + 4 * u + 2) * 136 + p] = (short)f2bf(v.z);
            VTl[(hf + 4 * u + 3) * 136 + p] = (short)f2bf(v.w);
        }
    }
    rpsL[t]       = refp[(size_t)b * 512 + t];
    rpsL[t + 256] = refp[(size_t)b * 512 + t + 256];

    // ================= Phase 1: logits + softmax -> attLb =================
    {
        const s16x8 aq = *(const s16x8*)(Qb +
            ((size_t)b * 64 + wq + col) * 256 + h * 32 + quad * 8);
        f32x4 lacc[8];
        #pragma unroll
        for (int t8 = 0; t8 < 8; ++t8) {
            const short* src = (t8 < 4)
                ? (Qb  + ((size_t)b * 64 + 16 * t8 + col) * 256)
                : (Khb + ((size_t)b * 64 + 16 * (t8 - 4) + col) * 256);
            const s16x8 bk = *(const s16x8*)(src + h * 32 + quad * 8);
            const f32x4 z = {0.f, 0.f, 0.f, 0.f};
            lacc[t8] = __builtin_amdgcn_mfma_f32_16x16x32_bf16(aq, bk, z, 0, 0, 0);
        }
        #pragma unroll
        for (int r = 0; r < 4; ++r) {
            float m = lacc[0][r];
            #pragma unroll
            for (int t8 = 1; t8 < 8; ++t8) m = fmaxf(m, lacc[t8][r]);
            #pragma unroll
            for (int s = 1; s < 16; s <<= 1) m = fmaxf(m, __shfl_xor(m, s, 64));
            float e[8], ssum = 0.f;
            #pragma unroll
            for (int t8 = 0; t8 < 8; ++t8) {
                e[t8] = __expf(lacc[t8][r] - m); ssum += e[t8];
            }
            #pragma unroll
            for (int s = 1; s < 16; s <<= 1) ssum += __shfl_xor(ssum, s, 64);
            const float inv = 1.0f / ssum;
            const int q = wq + 4 * quad + r;
            #pragma unroll
            for (int t8 = 0; t8 < 8; ++t8)
                attLb[q * 136 + 16 * t8 + col] = (short)f2bf(e[t8] * inv);
        }
    }

    // ================= Phase 2: offsets GEMM (OFF in registers) =============
    // wave owns n' in [64*wave, +64): acc[mi][nj]; q = 16mi+4quad+reg,
    // n' = 64*wave + 16nj + col.
    f32x4 acc[4][4] = {};
    for (int kq = 0; kq < 4; ++kq) {
        s16x8 afp[4][2];                        // A-frags direct from Qb (L2)
        #pragma unroll
        for (int mi = 0; mi < 4; ++mi)
            #pragma unroll
            for (int ks = 0; ks < 2; ++ks)
                afp[mi][ks] = *(const s16x8*)(Qb +
                    ((size_t)b * 64 + 16 * mi + col) * 256
                    + kq * 64 + ks * 32 + quad * 8);
        #pragma unroll
        for (int u = 0; u < 8; ++u) {           // stage Bsl[4][64][72] <- Wtb
            const int g = t + 256 * u;
            const int w = g >> 9, rowu = (g >> 3) & 63, koff = (g & 7) * 8;
            *(s16x8*)&Bsl[(w * 64 + rowu) * 72 + koff] =
                *(const s16x8*)(Wtb + (size_t)(h * 256 + w * 64 + rowu) * 256
                                + kq * 64 + koff);
        }
        __syncthreads();
        #pragma unroll
        for (int ks = 0; ks < 2; ++ks) {
            s16x8 bf[4];
            #pragma unroll
            for (int nj = 0; nj < 4; ++nj)
                bf[nj] = *(const s16x8*)&Bsl[(wave * 64 + 16 * nj + col) * 72
                                             + ks * 32 + quad * 8];
            #pragma unroll
            for (int mi = 0; mi < 4; ++mi)
                #pragma unroll
                for (int nj = 0; nj < 4; ++nj)
                    acc[mi][nj] = __builtin_amdgcn_mfma_f32_16x16x32_bf16(
                        afp[mi][ks], bf[nj], acc[mi][nj], 0, 0, 0);
        }
        __syncthreads();
    }

    // ================= Phase 3: zero Am, scatter =================
    {
        #pragma unroll
        for (int u = 0; u < 33; ++u) AmU[t + 256 * u] = 0.f;
    }
    __syncthreads();
    {
        const int i   = col >> 1;          // f-sub 0..7 ; rp level = (f&3)
        const int par = col & 1;           // 0: regs {0,1}, 1: regs {2,3}
        const int base = 32 * wave;        // image level = f>>5 = wave
        #pragma unroll
        for (int nj = 0; nj < 4; ++nj) {
            const float bj = bias[h * 256 + wave * 64 + 16 * nj + col];
            const int f = 32 * wave + 8 * nj + i;
            #pragma unroll
            for (int mi = 0; mi < 4; ++mi) {
                float v[4], p[4];
                #pragma unroll
                for (int r = 0; r < 4; ++r) v[r] = acc[mi][nj][r] + bj;
                #pragma unroll
                for (int r = 0; r < 4; ++r) p[r] = __shfl_xor(v[r], 1, 64);
                #pragma unroll
                for (int rs = 0; rs < 2; ++rs) {
                    const int r = par * 2 + rs;
                    const float ox = par ? p[r] : v[r];
                    const float oy = par ? v[r] : p[r];
                    const int q = 16 * mi + 4 * quad + r;
                    const float2 rp = *(const float2*)&rpsL[q * 8 + (i & 3) * 2];
                    const float a = bf2f((unsigned short)attLb[q * 136 + f]);
                    const float gx = 8.f * (rp.x + ox * 0.125f) - 0.5f;
                    const float gy = 4.f * (rp.y + oy * 0.25f) - 0.5f;
                    const float x0f = floorf(gx), y0f = floorf(gy);
                    const float wx = gx - x0f, wy = gy - y0f;
                    const int x0 = (int)x0f, y0 = (int)y0f;
                    float* rowW = &Am[q * 132 + base];
                    const bool xv0 = (x0 >= 0) && (x0 < 8);
                    const bool xv1 = (x0 >= -1) && (x0 < 7);
                    const bool yv0 = (y0 >= 0) && (y0 < 4);
                    const bool yv1 = (y0 >= -1) && (y0 < 3);
                    if (xv0 && yv0) unsafeAtomicAdd(&rowW[y0 * 8 + x0],           a * (1.f - wx) * (1.f - wy));
                    if (xv1 && yv0) unsafeAtomicAdd(&rowW[y0 * 8 + x0 + 1],       a * wx * (1.f - wy));
                    if (xv0 && yv1) unsafeAtomicAdd(&rowW[(y0 + 1) * 8 + x0],     a * (1.f - wx) * wy);
                    if (xv1 && yv1) unsafeAtomicAdd(&rowW[(y0 + 1) * 8 + x0 + 1], a * wx * wy);
                }
            }
        }
    }
    __syncthreads();

    // ================= Phase 4: Am -> bf16, AV, output =================
    {
        const int cq = t >> 2, cc = (t & 3) * 32;
        float vreg[32];
        #pragma unroll
        for (int u = 0; u < 8; ++u) {
            const float4 v = *(const float4*)&Am[cq * 132 + cc + 4 * u];
            vreg[4 * u + 0] = v.x; vreg[4 * u + 1] = v.y;
            vreg[4 * u + 2] = v.z; vreg[4 * u + 3] = v.w;
        }
        __syncthreads();
        #pragma unroll
        for (int u = 0; u < 4; ++u) {
            s16x8 o;
            #pragma unroll
            for (int j = 0; j < 8; ++j) o[j] = (short)f2bf(vreg[u * 8 + j]);
            *(s16x8*)&Amb[cq * 136 + cc + u * 8] = o;
        }
    }
    __syncthreads();
    {
        f32x4 oacc[2] = {};
        #pragma unroll
        for (int ks = 0; ks < 4; ++ks) {
            const s16x8 af = *(const s16x8*)&Amb[(wq + col) * 136 + ks * 32 + quad * 8];
            #pragma unroll
            for (int n2 = 0; n2 < 2; ++n2) {
                const s16x8 bv = *(const s16x8*)&VTl[(n2 * 16 + col) * 136
                                                     + ks * 32 + quad * 8];
                oacc[n2] = __builtin_amdgcn_mfma_f32_16x16x32_bf16(af, bv, oacc[n2], 0, 0, 0);
            }
        }
        #pragma unroll
        for (int n2 = 0; n2 < 2; ++n2) {
            const int d = h * 32 + n2 * 16 + col;
            #pragma unroll
            for (int pr = 0; pr < 2; ++pr) {
                const float avg = 0.5f * (oacc[n2][2 * pr] + oacc[n2][2 * pr + 1]);
                const int pj = wave * 8 + quad * 2 + pr;
                const size_t re = ((size_t)b * 64 + pj) * 256 + d;
                const size_t ro = ((size_t)b * 64 + pj + 32) * 256 + d;
                out[re] = query[re] + avg;
                out[ro] = query[ro] + avg;
            }
        }
    }
}

extern "C" void kernel_launch(void* const* d_in, const int* in_sizes, int n_in,
                              void* d_out, int out_size, void* d_ws, size_t ws_size,
                              hipStream_t stream) {
    (void)in_sizes; (void)n_in; (void)out_size; (void)ws_size;
    const float* query      = (const float*)d_in[0];
    const float* key_hist   = (const float*)d_in[1];
    const float* value_hist = (const float*)d_in[2];
    const float* refp       = (const float*)d_in[3];
    const float* W_off      = (const float*)d_in[5];
    const float* b_off      = (const float*)d_in[6];

    char* ws = (char*)d_ws;
    short* Wtb = (short*)(ws);                 // 1 MB
    short* Qb  = (short*)(ws + (1u << 20));    // 2 MB
    short* Khb = (short*)(ws + (3u << 20));    // 2 MB
    float* out = (float*)d_out;

    prep<<<2560, 256, 0, stream>>>(W_off, query, key_hist, Wtb, Qb, Khb);
    mega2<<<dim3(8, 64), 256, 0, stream>>>(query, value_hist, refp,
                                           Qb, Khb, Wtb, b_off, out);
}